// Round 4
// baseline (68.725 us; speedup 1.0000x reference)
//
#include <hip/hip_runtime.h>

// RecalcDistances: dist[v,k] = || select(nidx[v,k]>=0, coords[nidx[v,k]], 0) - coords[v] ||^2
// V=200000, K=64, C=4. Gather-latency-bound: 12.8M random 16B gathers into a
// 3.2MB coords table (L2-resident if we don't thrash it).
//
// Round 3: ILP=4 grid-stride (16 gathers in flight/thread) + nontemporal
// hints (via clang ext_vector types — HIP_vector_type is rejected by the
// builtin) on the streaming nidx-read and out-write so coords stays
// L2-resident.

typedef int   vint4   __attribute__((ext_vector_type(4)));
typedef float vfloat4 __attribute__((ext_vector_type(4)));

template<int ILP>
__global__ __launch_bounds__(256) void RecalcDistances_kernel(
    const float4*  __restrict__ coords,   // [V] float4
    const vint4*   __restrict__ nidx,     // [V*K/4] int4
    vfloat4*       __restrict__ out,      // [V*K/4] float4
    int total_groups,                     // V * K/4
    int groups_per_row,                   // K/4
    int stride)                           // total threads in grid
{
    int tid = blockIdx.x * blockDim.x + threadIdx.x;

    // Phase 1: issue all streaming loads (idx + own coords) up front.
    int    g[ILP];
    bool   ok[ILP];
    vint4  idx[ILP];
    float4 c[ILP];
#pragma unroll
    for (int i = 0; i < ILP; ++i) {
        g[i]  = tid + i * stride;
        ok[i] = (g[i] < total_groups);
        if (ok[i]) {
            idx[i] = __builtin_nontemporal_load(&nidx[g[i]]);
            c[i]   = coords[g[i] / groups_per_row];
        }
    }

    // Phase 2: per group, 4 independent gathers -> compute -> nt store.
#pragma unroll
    for (int i = 0; i < ILP; ++i) {
        if (!ok[i]) continue;
        float4 n0 = (idx[i].x >= 0) ? coords[idx[i].x] : make_float4(0.f,0.f,0.f,0.f);
        float4 n1 = (idx[i].y >= 0) ? coords[idx[i].y] : make_float4(0.f,0.f,0.f,0.f);
        float4 n2 = (idx[i].z >= 0) ? coords[idx[i].z] : make_float4(0.f,0.f,0.f,0.f);
        float4 n3 = (idx[i].w >= 0) ? coords[idx[i].w] : make_float4(0.f,0.f,0.f,0.f);

        vfloat4 r;
        {
            float dx = n0.x - c[i].x, dy = n0.y - c[i].y, dz = n0.z - c[i].z, dw = n0.w - c[i].w;
            r.x = dx*dx + dy*dy + dz*dz + dw*dw;
        }
        {
            float dx = n1.x - c[i].x, dy = n1.y - c[i].y, dz = n1.z - c[i].z, dw = n1.w - c[i].w;
            r.y = dx*dx + dy*dy + dz*dz + dw*dw;
        }
        {
            float dx = n2.x - c[i].x, dy = n2.y - c[i].y, dz = n2.z - c[i].z, dw = n2.w - c[i].w;
            r.z = dx*dx + dy*dy + dz*dz + dw*dw;
        }
        {
            float dx = n3.x - c[i].x, dy = n3.y - c[i].y, dz = n3.z - c[i].z, dw = n3.w - c[i].w;
            r.w = dx*dx + dy*dy + dz*dz + dw*dw;
        }
        __builtin_nontemporal_store(r, &out[g[i]]);
    }
}

extern "C" void kernel_launch(void* const* d_in, const int* in_sizes, int n_in,
                              void* d_out, int out_size, void* d_ws, size_t ws_size,
                              hipStream_t stream) {
    const float4* coords = (const float4*)d_in[0];
    const vint4*  nidx   = (const vint4*)d_in[1];
    vfloat4*      out    = (vfloat4*)d_out;

    const int C = 4;
    int V = in_sizes[0] / C;          // 200000
    int K = in_sizes[1] / V;          // 64
    int groups_per_row = K / 4;       // 16
    int total_groups = V * groups_per_row;

    constexpr int ILP = 4;
    int block = 256;
    int nthreads = (total_groups + ILP - 1) / ILP;
    int grid = (nthreads + block - 1) / block;
    int stride = grid * block;
    RecalcDistances_kernel<ILP><<<grid, block, 0, stream>>>(
        coords, nidx, out, total_groups, groups_per_row, stride);
}

// Round 5
// 68.593 us; speedup vs baseline: 1.0019x; 1.0019x over previous
//
#include <hip/hip_runtime.h>

// RecalcDistances: dist[v,k] = || select(nidx[v,k]>=0, coords[nidx[v,k]], 0) - coords[v] ||^2
// V=200000, K=64, C=4. Gather-latency-bound: 12.8M random 16B gathers into a
// 3.2MB coords table (L2-resident if we don't thrash it).
//
// Round 3: ILP=4 grid-stride (16 gathers in flight/thread) + nontemporal
// hints (via clang ext_vector types — HIP_vector_type is rejected by the
// builtin) on the streaming nidx-read and out-write so coords stays
// L2-resident.

typedef int   vint4   __attribute__((ext_vector_type(4)));
typedef float vfloat4 __attribute__((ext_vector_type(4)));

template<int ILP>
__global__ __launch_bounds__(256) void RecalcDistances_kernel(
    const float4*  __restrict__ coords,   // [V] float4
    const vint4*   __restrict__ nidx,     // [V*K/4] int4
    vfloat4*       __restrict__ out,      // [V*K/4] float4
    int total_groups,                     // V * K/4
    int groups_per_row,                   // K/4
    int stride)                           // total threads in grid
{
    int tid = blockIdx.x * blockDim.x + threadIdx.x;

    // Phase 1: issue all streaming loads (idx + own coords) up front.
    int    g[ILP];
    bool   ok[ILP];
    vint4  idx[ILP];
    float4 c[ILP];
#pragma unroll
    for (int i = 0; i < ILP; ++i) {
        g[i]  = tid + i * stride;
        ok[i] = (g[i] < total_groups);
        if (ok[i]) {
            idx[i] = __builtin_nontemporal_load(&nidx[g[i]]);
            c[i]   = coords[g[i] / groups_per_row];
        }
    }

    // Phase 2: per group, 4 independent gathers -> compute -> nt store.
#pragma unroll
    for (int i = 0; i < ILP; ++i) {
        if (!ok[i]) continue;
        float4 n0 = (idx[i].x >= 0) ? coords[idx[i].x] : make_float4(0.f,0.f,0.f,0.f);
        float4 n1 = (idx[i].y >= 0) ? coords[idx[i].y] : make_float4(0.f,0.f,0.f,0.f);
        float4 n2 = (idx[i].z >= 0) ? coords[idx[i].z] : make_float4(0.f,0.f,0.f,0.f);
        float4 n3 = (idx[i].w >= 0) ? coords[idx[i].w] : make_float4(0.f,0.f,0.f,0.f);

        vfloat4 r;
        {
            float dx = n0.x - c[i].x, dy = n0.y - c[i].y, dz = n0.z - c[i].z, dw = n0.w - c[i].w;
            r.x = dx*dx + dy*dy + dz*dz + dw*dw;
        }
        {
            float dx = n1.x - c[i].x, dy = n1.y - c[i].y, dz = n1.z - c[i].z, dw = n1.w - c[i].w;
            r.y = dx*dx + dy*dy + dz*dz + dw*dw;
        }
        {
            float dx = n2.x - c[i].x, dy = n2.y - c[i].y, dz = n2.z - c[i].z, dw = n2.w - c[i].w;
            r.z = dx*dx + dy*dy + dz*dz + dw*dw;
        }
        {
            float dx = n3.x - c[i].x, dy = n3.y - c[i].y, dz = n3.z - c[i].z, dw = n3.w - c[i].w;
            r.w = dx*dx + dy*dy + dz*dz + dw*dw;
        }
        __builtin_nontemporal_store(r, &out[g[i]]);
    }
}

extern "C" void kernel_launch(void* const* d_in, const int* in_sizes, int n_in,
                              void* d_out, int out_size, void* d_ws, size_t ws_size,
                              hipStream_t stream) {
    const float4* coords = (const float4*)d_in[0];
    const vint4*  nidx   = (const vint4*)d_in[1];
    vfloat4*      out    = (vfloat4*)d_out;

    const int C = 4;
    int V = in_sizes[0] / C;          // 200000
    int K = in_sizes[1] / V;          // 64
    int groups_per_row = K / 4;       // 16
    int total_groups = V * groups_per_row;

    constexpr int ILP = 4;
    int block = 256;
    int nthreads = (total_groups + ILP - 1) / ILP;
    int grid = (nthreads + block - 1) / block;
    int stride = grid * block;
    RecalcDistances_kernel<ILP><<<grid, block, 0, stream>>>(
        coords, nidx, out, total_groups, groups_per_row, stride);
}

// Round 6
// 66.237 us; speedup vs baseline: 1.0376x; 1.0356x over previous
//
#include <hip/hip_runtime.h>

// RecalcDistances: dist[v,k] = || select(nidx[v,k]>=0, coords[nidx[v,k]], 0) - coords[v] ||^2
// V=200000, K=64, C=4.
//
// Model (r5): latency-bound random gather into a 3.2MB L2-resident table.
// Throughput = outstanding_requests / latency. Round 3's branchy ILP blocked
// load hoisting. This round: branchless ILP=2, all loads issued up front
// (12 VMEM in flight per wave), select via max+cndmask, div -> shift,
// nontemporal on the nidx/out streams so coords keeps L2.

typedef int   vint4   __attribute__((ext_vector_type(4)));
typedef float vfloat4 __attribute__((ext_vector_type(4)));

__device__ __forceinline__ float sqdist(vfloat4 n, vfloat4 c, bool valid) {
    // invalid neighbor => ncoords = 0 => dist = |c|^2
    n = valid ? n : (vfloat4)(0.f, 0.f, 0.f, 0.f);
    float dx = n.x - c.x, dy = n.y - c.y, dz = n.z - c.z, dw = n.w - c.w;
    return dx * dx + dy * dy + dz * dz + dw * dw;
}

// EXACT=true: total_groups == 2*stride, no bounds checks, no branches.
template<bool EXACT>
__global__ __launch_bounds__(256) void RecalcDistances_kernel(
    const vfloat4* __restrict__ coords,   // [V]
    const vint4*   __restrict__ nidx,     // [V*K/4]
    vfloat4*       __restrict__ out,      // [V*K/4]
    int total_groups,                     // V*K/4
    int shift,                            // log2(K/4)
    int stride)                           // total threads
{
    int tid = blockIdx.x * blockDim.x + threadIdx.x;
    int g0 = tid;
    int g1 = tid + stride;

    bool ok1 = EXACT || (g1 < total_groups);
    if (!EXACT && g0 >= total_groups) return;

    // ---- issue ALL independent loads before any use ----
    vint4 i0 = __builtin_nontemporal_load(&nidx[g0]);
    vint4 i1 = ok1 ? __builtin_nontemporal_load(&nidx[g1]) : (vint4)(0, 0, 0, 0);
    vfloat4 c0 = coords[g0 >> shift];
    vfloat4 c1 = coords[(ok1 ? g1 : g0) >> shift];

    // clamp negative indices to 0 so the gathers are unconditional
    int s00 = max(i0.x, 0), s01 = max(i0.y, 0), s02 = max(i0.z, 0), s03 = max(i0.w, 0);
    int s10 = max(i1.x, 0), s11 = max(i1.y, 0), s12 = max(i1.z, 0), s13 = max(i1.w, 0);

    vfloat4 n00 = coords[s00];
    vfloat4 n01 = coords[s01];
    vfloat4 n02 = coords[s02];
    vfloat4 n03 = coords[s03];
    vfloat4 n10 = coords[s10];
    vfloat4 n11 = coords[s11];
    vfloat4 n12 = coords[s12];
    vfloat4 n13 = coords[s13];

    // ---- compute + store ----
    vfloat4 r0;
    r0.x = sqdist(n00, c0, i0.x >= 0);
    r0.y = sqdist(n01, c0, i0.y >= 0);
    r0.z = sqdist(n02, c0, i0.z >= 0);
    r0.w = sqdist(n03, c0, i0.w >= 0);
    __builtin_nontemporal_store(r0, &out[g0]);

    vfloat4 r1;
    r1.x = sqdist(n10, c1, i1.x >= 0);
    r1.y = sqdist(n11, c1, i1.y >= 0);
    r1.z = sqdist(n12, c1, i1.z >= 0);
    r1.w = sqdist(n13, c1, i1.w >= 0);
    if (ok1) __builtin_nontemporal_store(r1, &out[g1]);
}

extern "C" void kernel_launch(void* const* d_in, const int* in_sizes, int n_in,
                              void* d_out, int out_size, void* d_ws, size_t ws_size,
                              hipStream_t stream) {
    const vfloat4* coords = (const vfloat4*)d_in[0];
    const vint4*   nidx   = (const vint4*)d_in[1];
    vfloat4*       out    = (vfloat4*)d_out;

    const int C = 4;
    int V = in_sizes[0] / C;          // 200000
    int K = in_sizes[1] / V;          // 64
    int groups_per_row = K / 4;       // 16
    int total_groups = V * groups_per_row;   // 3,200,000

    int shift = 0;
    while ((1 << shift) < groups_per_row) ++shift;   // log2(16) = 4

    const int ILP = 2;
    int block = 256;
    int nthreads = (total_groups + ILP - 1) / ILP;   // 1,600,000
    int grid = (nthreads + block - 1) / block;       // 6250
    int stride = grid * block;

    bool exact = (total_groups == 2 * stride) && ((1 << shift) == groups_per_row);
    if (exact) {
        RecalcDistances_kernel<true><<<grid, block, 0, stream>>>(
            coords, nidx, out, total_groups, shift, stride);
    } else {
        RecalcDistances_kernel<false><<<grid, block, 0, stream>>>(
            coords, nidx, out, total_groups, shift, stride);
    }
}

// Round 7
// 62.427 us; speedup vs baseline: 1.1009x; 1.0610x over previous
//
#include <hip/hip_runtime.h>

// RecalcDistances: dist[v,k] = || select(nidx[v,k]>=0, coords[nidx[v,k]], 0) - coords[v] ||^2
// V=200000, K=64, C=4.
//
// Final form (reverted to the best-measured Round-2 structure):
// One thread per int4 group of neighbors. All nidx/out accesses perfectly
// coalesced (16 B/lane); 4 independent random 16 B gathers per thread into
// the 3.2 MB L2-resident coords table.
//
// Why no further tricks: measured across ILP=1/2/4-group variants,
// nontemporal hints, and occupancy 55-72%, duration is pinned at 62-70 us.
// The limiter is divergent-gather request throughput (12.8M lane-requests
// ~= 1.6M/XCD-L2 at ~16 req/cy/XCD -> ~45-55 us floor + streaming), a
// saturated shared resource insensitive to per-wave concurrency. The
// simplest kernel (lowest VGPR=16, max occupancy, least address VALU) is
// the fastest timed variant (61.98 us).

__global__ __launch_bounds__(256) void RecalcDistances_kernel(
    const float4* __restrict__ coords,   // [V] float4
    const int4*   __restrict__ nidx,     // [V*K/4] int4
    float4*       __restrict__ out,      // [V*K/4] float4
    int total_groups,                    // V * K/4
    int groups_per_row)                  // K/4
{
    int tid = blockIdx.x * blockDim.x + threadIdx.x;
    if (tid >= total_groups) return;

    int v = tid / groups_per_row;
    float4 c = coords[v];
    int4 idx = nidx[tid];

    float4 r;
    {
        float4 n = (idx.x >= 0) ? coords[idx.x] : make_float4(0.f, 0.f, 0.f, 0.f);
        float dx = n.x - c.x, dy = n.y - c.y, dz = n.z - c.z, dw = n.w - c.w;
        r.x = dx * dx + dy * dy + dz * dz + dw * dw;
    }
    {
        float4 n = (idx.y >= 0) ? coords[idx.y] : make_float4(0.f, 0.f, 0.f, 0.f);
        float dx = n.x - c.x, dy = n.y - c.y, dz = n.z - c.z, dw = n.w - c.w;
        r.y = dx * dx + dy * dy + dz * dz + dw * dw;
    }
    {
        float4 n = (idx.z >= 0) ? coords[idx.z] : make_float4(0.f, 0.f, 0.f, 0.f);
        float dx = n.x - c.x, dy = n.y - c.y, dz = n.z - c.z, dw = n.w - c.w;
        r.z = dx * dx + dy * dy + dz * dz + dw * dw;
    }
    {
        float4 n = (idx.w >= 0) ? coords[idx.w] : make_float4(0.f, 0.f, 0.f, 0.f);
        float dx = n.x - c.x, dy = n.y - c.y, dz = n.z - c.z, dw = n.w - c.w;
        r.w = dx * dx + dy * dy + dz * dz + dw * dw;
    }

    out[tid] = r;
}

extern "C" void kernel_launch(void* const* d_in, const int* in_sizes, int n_in,
                              void* d_out, int out_size, void* d_ws, size_t ws_size,
                              hipStream_t stream) {
    const float4* coords = (const float4*)d_in[0];
    const int4*   nidx   = (const int4*)d_in[1];
    float4*       out    = (float4*)d_out;

    const int C = 4;
    int V = in_sizes[0] / C;          // 200000
    int K = in_sizes[1] / V;          // 64
    int groups_per_row = K / 4;       // 16
    int total_groups = V * groups_per_row;

    int block = 256;
    int grid = (total_groups + block - 1) / block;
    RecalcDistances_kernel<<<grid, block, 0, stream>>>(coords, nidx, out,
                                                       total_groups, groups_per_row);
}